// Round 11
// baseline (254.560 us; speedup 1.0000x reference)
//
#include <hip/hip_runtime.h>

// proj_splat: project 48^3 voxel grid into 8 camera feature maps (64ch, 64x64),
// bilinear-sample, write (8, 64, 48^3) fp32.
//
// Block = (camera, channel-pair, voxel-quarter). The 2 channel images live in
// LDS as channel-INTERLEAVED float2 (one ds_read_b64 per bilinear tap serves
// both channels), with a bank-conflict swizzle: row stride 66 float2 + XOR of
// the 4-float group index with (y&15). Row-major [64][64] f32 has bank = x%32
// (stride 64 = 0 mod 32), so steep epipolar lines made all 64 lanes hit one
// bank (up to 32-way, ~11x; measured ~6x avg -> 243us). Swizzle caps it ~2x.
// One barrier total; 108 free-running iters; nontemporal coalesced stores.

#define NR    8
#define FDIM  64
#define FH    64
#define FW    64
#define IMG   (FH * FW)            // 4096 floats = 16 KB per channel
#define NVOX  48
#define NV    (NVOX * NVOX * NVOX) // 110592
#define THREADS 256
#define QUARTERS 4
#define VPB   (NV / QUARTERS)      // 27648 voxels per block
#define ITERS (VPB / THREADS)      // 108
#define ROWS  64
#define RS    66                   // row stride in float2 units (pad: +4y into bank)

typedef float f32x4 __attribute__((ext_vector_type(4)));
typedef float f32x2 __attribute__((ext_vector_type(2)));

// swizzled float2-index of pixel (y,x): group-XOR keeps 4-float runs contiguous
__device__ __forceinline__ int swz(int y, int x) {
    const int g = ((x >> 2) ^ (y & 15));
    return y * RS + (g << 2) + (x & 3);
}

__global__ __launch_bounds__(THREADS, 4) void proj_splat_kernel(
    const float* __restrict__ feats,   // [NR][FDIM][IMG]
    const float* __restrict__ Kcam,    // [2][4][3][4]
    const float* __restrict__ vmax,    // [2][3]
    const float* __restrict__ vmin,    // [2][3]
    float* __restrict__ out)           // [NR][FDIM][NV]
{
    __shared__ f32x2 lds2[ROWS * RS];  // 64*66*8B = 33.8 KB -> 4 blocks/CU

    const int t  = threadIdx.x;
    const int cp = blockIdx.x;         // channel pair 0..31
    const int qq = blockIdx.y;         // voxel quarter 0..3
    const int r  = blockIdx.z;         // camera 0..7
    const int b  = r >> 2;             // batch

    // ---- stage both channel images, interleaved + swizzled ----
    const float* c0 = feats + ((size_t)r * FDIM + 2 * cp) * IMG;
    const float* c1 = c0 + IMG;
    float* ldsf = reinterpret_cast<float*>(lds2);
#pragma unroll
    for (int p = 0; p < 4; ++p) {
        const int i = p * 1024 + t * 4;      // linear pixel index, x = i&63 (mult of 4)
        const int y = i >> 6;
        const int x = i & 63;
        const f32x4 a = *reinterpret_cast<const f32x4*>(c0 + i);
        const f32x4 bb = *reinterpret_cast<const f32x4*>(c1 + i);
        const int fb = 2 * swz(y, x);        // float addr, 16B aligned (x%4==0)
        f32x4 s0 = { a.x, bb.x, a.y, bb.y };
        f32x4 s1 = { a.z, bb.z, a.w, bb.w };
        *reinterpret_cast<f32x4*>(ldsf + fb)     = s0;
        *reinterpret_cast<f32x4*>(ldsf + fb + 4) = s1;
    }
    __syncthreads();

    // ---- uniform per-block projection constants (SGPRs) ----
    const float inv = 1.0f / (float)(NVOX - 1);
    const float* vmn = vmin + b * 3;
    const float* vmx = vmax + b * 3;
    const float ax = (vmx[0] - vmn[0]) * inv;
    const float ay = (vmx[1] - vmn[1]) * inv;
    const float az = (vmx[2] - vmn[2]) * inv;
    const float* K = Kcam + r * 12;
    const float A0 = K[0] * ax, B0 = K[1] * ay, D0 = K[2]  * az;
    const float C0 = K[0] * vmn[0] + K[1] * vmn[1] + K[2]  * vmn[2] + K[3];
    const float A1 = K[4] * ax, B1 = K[5] * ay, D1 = K[6]  * az;
    const float C1 = K[4] * vmn[0] + K[5] * vmn[1] + K[6]  * vmn[2] + K[7];
    const float A2 = K[8] * ax, B2 = K[9] * ay, D2 = K[10] * az;
    const float C2 = K[8] * vmn[0] + K[9] * vmn[1] + K[10] * vmn[2] + K[11];

    float* o0 = out + ((size_t)r * FDIM + 2 * cp) * NV;
    float* o1 = o0 + NV;

    int n = qq * VPB + t;
    int i = n / (NVOX * NVOX);
    int j = (n / NVOX) % NVOX;
    int k = n % NVOX;

    for (int it = 0; it < ITERS; ++it) {
        const float fi = (float)i, fj = (float)j, fk = (float)k;
        const float px = C0 + A0 * fi + B0 * fj + D0 * fk;
        const float py = C1 + A1 * fi + B1 * fj + D1 * fk;
        const float pz = C2 + A2 * fi + B2 * fj + D2 * fk;

        const float rz = 0.25f / pz;       // rsz/z
        float imx = px * rz;
        float imy = py * rz;
        imx = fminf(fmaxf(imx, 0.0f), (float)(FW - 1));
        imy = fminf(fmaxf(imy, 0.0f), (float)(FH - 1));

        const float x0 = floorf(imx);
        const float x1 = fminf(x0 + 1.0f, (float)(FW - 1));
        const float y0 = floorf(imy);
        const float y1 = fminf(y0 + 1.0f, (float)(FH - 1));

        // reference weight formulas, literally (exact zeros at clamped edges)
        const float wa = (x1 - imx) * (y1 - imy);   // (y0,x0)
        const float wc = (imx - x0) * (y1 - imy);   // (y0,x1)
        const float wb = (x1 - imx) * (imy - y0);   // (y1,x0)
        const float wd = (imx - x0) * (imy - y0);   // (y1,x1)

        const int ix0 = (int)x0, ix1 = (int)x1;    // ix1 already clamped to 63
        const int iy0 = (int)y0, iy1 = (int)y1;

        // 4 taps, one ds_read_b64 each -> both channels
        const f32x2 p00 = lds2[swz(iy0, ix0)];
        const f32x2 p01 = lds2[swz(iy0, ix1)];
        const f32x2 p10 = lds2[swz(iy1, ix0)];
        const f32x2 p11 = lds2[swz(iy1, ix1)];

        const float res0 = wa * p00.x + wc * p01.x + wb * p10.x + wd * p11.x;
        const float res1 = wa * p00.y + wc * p01.y + wb * p10.y + wd * p11.y;
        __builtin_nontemporal_store(res0, o0 + n);
        __builtin_nontemporal_store(res1, o1 + n);

        // advance by THREADS=256 = 5*48 + 16 in (i,j,k)
        n += THREADS;
        k += 16;
        if (k >= NVOX) { k -= NVOX; j += 6; } else { j += 5; }
        if (j >= NVOX) { j -= NVOX; i += 1; }
    }
}

extern "C" void kernel_launch(void* const* d_in, const int* in_sizes, int n_in,
                              void* d_out, int out_size, void* d_ws, size_t ws_size,
                              hipStream_t stream) {
    const float* feats = (const float*)d_in[0];
    const float* Kcam  = (const float*)d_in[1];
    const float* vmax  = (const float*)d_in[2];
    const float* vmin  = (const float*)d_in[3];
    // d_in[4] = nvox (48), baked in as NVOX
    float* out = (float*)d_out;

    dim3 grid(FDIM / 2, QUARTERS, NR);   // 32 x 4 x 8 = 1024 blocks
    dim3 block(THREADS);
    proj_splat_kernel<<<grid, block, 0, stream>>>(feats, Kcam, vmax, vmin, out);
}

// Round 12
// 233.099 us; speedup vs baseline: 1.0921x; 1.0921x over previous
//
#include <hip/hip_runtime.h>

// proj_splat: project 48^3 voxel grid into 8 camera feature maps (64ch, 64x64),
// bilinear-sample, write (8, 64, 48^3) fp32.
//
// Block = (camera, 4-channel group, voxel quarter). The 4 channel images are
// staged in LDS pixel-major as f32x4 {c0,c1,c2,c3}[pixel] (64 KB), slot index
// XOR-swizzled: slot = 64*y + (x ^ (y&7)) — breaks the steep-epipolar case
// where all 64 lanes hit the same 8-pixel bank group. One ds_read_b128 per
// bilinear tap serves 4 channels; projection VALU amortized over 4 channels.
// One barrier; 54 free-running iters; plain coalesced scalar stores.
// 512 blocks x 512 thr = 2 blocks/CU (LDS-bound), 16 waves/CU.

#define NR    8
#define FDIM  64
#define FH    64
#define FW    64
#define IMG   (FH * FW)            // 4096 pixels
#define NVOX  48
#define NV    (NVOX * NVOX * NVOX) // 110592
#define THREADS 512
#define QUARTERS 4
#define VPB   (NV / QUARTERS)      // 27648 voxels per block
#define ITERS (VPB / THREADS)      // 54

typedef float f32x4 __attribute__((ext_vector_type(4)));

// xor-swizzled pixel slot: stays in [0,4096) since x^b (b<8) stays in [0,64)
__device__ __forceinline__ int slotof(int y, int x) {
    return (y << 6) + (x ^ (y & 7));
}

__global__ __launch_bounds__(THREADS, 4) void proj_splat_kernel(
    const float* __restrict__ feats,   // [NR][FDIM][IMG]
    const float* __restrict__ Kcam,    // [2][4][3][4]
    const float* __restrict__ vmax,    // [2][3]
    const float* __restrict__ vmin,    // [2][3]
    float* __restrict__ out)           // [NR][FDIM][NV]
{
    __shared__ f32x4 lds4[IMG];        // 65536 B: pixel-major, 4ch interleaved

    const int t  = threadIdx.x;
    const int cg = blockIdx.x;         // channel group 0..15 (4 channels each)
    const int qq = blockIdx.y;         // voxel quarter 0..3
    const int r  = blockIdx.z;         // camera 0..7
    const int b  = r >> 2;             // batch

    // ---- stage 4 channel images -> pixel-major interleaved, swizzled ----
    const float* s0 = feats + ((size_t)r * FDIM + cg * 4) * IMG;
    const float* s1 = s0 + IMG;
    const float* s2 = s1 + IMG;
    const float* s3 = s2 + IMG;
#pragma unroll
    for (int q = 0; q < 2; ++q) {
        const int i = q * 2048 + t * 4;       // pixel index, multiple of 4
        const int y = i >> 6, x = i & 63;
        const f32x4 a  = *reinterpret_cast<const f32x4*>(s0 + i);
        const f32x4 bb = *reinterpret_cast<const f32x4*>(s1 + i);
        const f32x4 c  = *reinterpret_cast<const f32x4*>(s2 + i);
        const f32x4 d  = *reinterpret_cast<const f32x4*>(s3 + i);
#pragma unroll
        for (int m = 0; m < 4; ++m) {
            f32x4 v = { a[m], bb[m], c[m], d[m] };
            lds4[slotof(y, x + m)] = v;
        }
    }
    __syncthreads();

    // ---- uniform per-block projection constants (SGPRs) ----
    const float inv = 1.0f / (float)(NVOX - 1);
    const float* vmn = vmin + b * 3;
    const float* vmx = vmax + b * 3;
    const float ax = (vmx[0] - vmn[0]) * inv;
    const float ay = (vmx[1] - vmn[1]) * inv;
    const float az = (vmx[2] - vmn[2]) * inv;
    const float* K = Kcam + r * 12;
    const float A0 = K[0] * ax, B0 = K[1] * ay, D0 = K[2]  * az;
    const float C0 = K[0] * vmn[0] + K[1] * vmn[1] + K[2]  * vmn[2] + K[3];
    const float A1 = K[4] * ax, B1 = K[5] * ay, D1 = K[6]  * az;
    const float C1 = K[4] * vmn[0] + K[5] * vmn[1] + K[6]  * vmn[2] + K[7];
    const float A2 = K[8] * ax, B2 = K[9] * ay, D2 = K[10] * az;
    const float C2 = K[8] * vmn[0] + K[9] * vmn[1] + K[10] * vmn[2] + K[11];

    float* o0 = out + ((size_t)r * FDIM + cg * 4) * NV;
    float* o1 = o0 + NV;
    float* o2 = o1 + NV;
    float* o3 = o2 + NV;

    int n = qq * VPB + t;
    int i = n / (NVOX * NVOX);
    int j = (n / NVOX) % NVOX;
    int k = n % NVOX;

    for (int it = 0; it < ITERS; ++it) {
        const float fi = (float)i, fj = (float)j, fk = (float)k;
        const float px = C0 + A0 * fi + B0 * fj + D0 * fk;
        const float py = C1 + A1 * fi + B1 * fj + D1 * fk;
        const float pz = C2 + A2 * fi + B2 * fj + D2 * fk;

        const float rz = 0.25f / pz;       // rsz/z
        float imx = px * rz;
        float imy = py * rz;
        imx = fminf(fmaxf(imx, 0.0f), (float)(FW - 1));
        imy = fminf(fmaxf(imy, 0.0f), (float)(FH - 1));

        const float x0 = floorf(imx);
        const float x1 = fminf(x0 + 1.0f, (float)(FW - 1));
        const float y0 = floorf(imy);
        const float y1 = fminf(y0 + 1.0f, (float)(FH - 1));

        // reference weight formulas, literally (exact zeros at clamped edges)
        const float wa = (x1 - imx) * (y1 - imy);   // (y0,x0)
        const float wc = (imx - x0) * (y1 - imy);   // (y0,x1)
        const float wb = (x1 - imx) * (imy - y0);   // (y1,x0)
        const float wd = (imx - x0) * (imy - y0);   // (y1,x1)

        const int ix0 = (int)x0, ix1 = (int)x1;    // ix1/iy1 pre-clamped to 63
        const int iy0 = (int)y0, iy1 = (int)y1;

        // 4 taps, one ds_read_b128 each -> 4 channels
        const f32x4 p00 = lds4[slotof(iy0, ix0)];
        const f32x4 p01 = lds4[slotof(iy0, ix1)];
        const f32x4 p10 = lds4[slotof(iy1, ix0)];
        const f32x4 p11 = lds4[slotof(iy1, ix1)];

        const f32x4 res = wa * p00 + wc * p01 + wb * p10 + wd * p11;
        o0[n] = res.x;
        o1[n] = res.y;
        o2[n] = res.z;
        o3[n] = res.w;

        // advance by THREADS=512 = 10*48 + 32 in (i,j,k)
        n += THREADS;
        k += 32;
        if (k >= NVOX) { k -= NVOX; j += 11; } else { j += 10; }
        if (j >= NVOX) { j -= NVOX; i += 1; }
    }
}

extern "C" void kernel_launch(void* const* d_in, const int* in_sizes, int n_in,
                              void* d_out, int out_size, void* d_ws, size_t ws_size,
                              hipStream_t stream) {
    const float* feats = (const float*)d_in[0];
    const float* Kcam  = (const float*)d_in[1];
    const float* vmax  = (const float*)d_in[2];
    const float* vmin  = (const float*)d_in[3];
    // d_in[4] = nvox (48), baked in as NVOX
    float* out = (float*)d_out;

    dim3 grid(FDIM / 4, QUARTERS, NR);   // 16 x 4 x 8 = 512 blocks
    dim3 block(THREADS);
    proj_splat_kernel<<<grid, block, 0, stream>>>(feats, Kcam, vmax, vmin, out);
}

// Round 13
// 231.208 us; speedup vs baseline: 1.1010x; 1.0082x over previous
//
#include <hip/hip_runtime.h>

// proj_splat: project 48^3 voxel grid into 8 camera feature maps (64ch, 64x64),
// bilinear-sample, write (8, 64, 48^3) fp32.
//
// Block = (camera, 4-channel group, voxel quarter); 512 thr; 64 KB LDS holds 4
// channel images pixel-major interleaved (f32x4 per pixel, slot XOR-swizzled).
// Each thread-iter: 2 consecutive-k voxels x 4 channels. Projection for voxel2
// is incremental (+D). rcp instead of divide. One ds_read_b128 per tap serves
// 4 channels; f32x2 stores per channel (consecutive n). One barrier, 27 iters.

#define NR    8
#define FDIM  64
#define FH    64
#define FW    64
#define IMG   (FH * FW)            // 4096 pixels
#define NVOX  48
#define NV    (NVOX * NVOX * NVOX) // 110592
#define THREADS 512
#define QUARTERS 4
#define VPB   (NV / QUARTERS)      // 27648
#define ITERS (VPB / (THREADS * 2)) // 27

typedef float f32x4 __attribute__((ext_vector_type(4)));
typedef float f32x2 __attribute__((ext_vector_type(2)));

// xor-swizzled pixel slot: breaks the steep-epipolar same-bank-group case.
// x^b (b<8) stays in [0,64), so slot stays in [0,4096).
__device__ __forceinline__ int slotof(int y, int x) {
    return (y << 6) + (x ^ (y & 7));
}

// bilinear sample of the 4-channel interleaved LDS image at projected (px,py,pz)
__device__ __forceinline__ f32x4 sample(const f32x4* __restrict__ lds4,
                                        float px, float py, float pz) {
    const float rz = __builtin_amdgcn_rcpf(pz) * 0.25f;   // rsz/z, approx (1ulp)
    float imx = px * rz;
    float imy = py * rz;
    imx = fminf(fmaxf(imx, 0.0f), (float)(FW - 1));
    imy = fminf(fmaxf(imy, 0.0f), (float)(FH - 1));

    const float x0 = floorf(imx);
    const float x1 = fminf(x0 + 1.0f, (float)(FW - 1));
    const float y0 = floorf(imy);
    const float y1 = fminf(y0 + 1.0f, (float)(FH - 1));

    // reference weight formulas, literally (exact zeros at clamped edges)
    const float wa = (x1 - imx) * (y1 - imy);   // (y0,x0)
    const float wc = (imx - x0) * (y1 - imy);   // (y0,x1)
    const float wb = (x1 - imx) * (imy - y0);   // (y1,x0)
    const float wd = (imx - x0) * (imy - y0);   // (y1,x1)

    const int ix0 = (int)x0, ix1 = (int)x1;
    const int iy0 = (int)y0, iy1 = (int)y1;

    const f32x4 p00 = lds4[slotof(iy0, ix0)];
    const f32x4 p01 = lds4[slotof(iy0, ix1)];
    const f32x4 p10 = lds4[slotof(iy1, ix0)];
    const f32x4 p11 = lds4[slotof(iy1, ix1)];

    return wa * p00 + wc * p01 + wb * p10 + wd * p11;
}

__global__ __launch_bounds__(THREADS, 4) void proj_splat_kernel(
    const float* __restrict__ feats,   // [NR][FDIM][IMG]
    const float* __restrict__ Kcam,    // [2][4][3][4]
    const float* __restrict__ vmax,    // [2][3]
    const float* __restrict__ vmin,    // [2][3]
    float* __restrict__ out)           // [NR][FDIM][NV]
{
    __shared__ f32x4 lds4[IMG];        // 64 KB: pixel-major, 4ch interleaved

    const int t  = threadIdx.x;
    const int cg = blockIdx.x;         // channel group 0..15
    const int qq = blockIdx.y;         // voxel quarter 0..3
    const int r  = blockIdx.z;         // camera 0..7
    const int b  = r >> 2;             // batch

    // ---- stage 4 channel images -> pixel-major interleaved, swizzled ----
    const float* s0 = feats + ((size_t)r * FDIM + cg * 4) * IMG;
    const float* s1 = s0 + IMG;
    const float* s2 = s1 + IMG;
    const float* s3 = s2 + IMG;
#pragma unroll
    for (int q = 0; q < 2; ++q) {
        const int idx = q * 2048 + t * 4;     // pixel index, multiple of 4
        const int y = idx >> 6, x = idx & 63;
        const f32x4 a  = *reinterpret_cast<const f32x4*>(s0 + idx);
        const f32x4 bb = *reinterpret_cast<const f32x4*>(s1 + idx);
        const f32x4 c  = *reinterpret_cast<const f32x4*>(s2 + idx);
        const f32x4 d  = *reinterpret_cast<const f32x4*>(s3 + idx);
#pragma unroll
        for (int m = 0; m < 4; ++m) {
            f32x4 v = { a[m], bb[m], c[m], d[m] };
            lds4[slotof(y, x + m)] = v;
        }
    }
    __syncthreads();

    // ---- uniform per-block projection constants (SGPRs) ----
    const float inv = 1.0f / (float)(NVOX - 1);
    const float* vmn = vmin + b * 3;
    const float* vmx = vmax + b * 3;
    const float ax = (vmx[0] - vmn[0]) * inv;
    const float ay = (vmx[1] - vmn[1]) * inv;
    const float az = (vmx[2] - vmn[2]) * inv;
    const float* K = Kcam + r * 12;
    const float A0 = K[0] * ax, B0 = K[1] * ay, D0 = K[2]  * az;
    const float C0 = K[0] * vmn[0] + K[1] * vmn[1] + K[2]  * vmn[2] + K[3];
    const float A1 = K[4] * ax, B1 = K[5] * ay, D1 = K[6]  * az;
    const float C1 = K[4] * vmn[0] + K[5] * vmn[1] + K[6]  * vmn[2] + K[7];
    const float A2 = K[8] * ax, B2 = K[9] * ay, D2 = K[10] * az;
    const float C2 = K[8] * vmn[0] + K[9] * vmn[1] + K[10] * vmn[2] + K[11];

    float* o0 = out + ((size_t)r * FDIM + cg * 4) * NV;
    float* o1 = o0 + NV;
    float* o2 = o1 + NV;
    float* o3 = o2 + NV;

    // thread handles voxel pair (n, n+1): n even, k pair stays in-row (48 even)
    int n = qq * VPB + 2 * t;
    int i = n / (NVOX * NVOX);
    int j = (n / NVOX) % NVOX;
    int k = n % NVOX;

    for (int it = 0; it < ITERS; ++it) {
        const float fi = (float)i, fj = (float)j, fk = (float)k;
        const float px0 = C0 + A0 * fi + B0 * fj + D0 * fk;
        const float py0 = C1 + A1 * fi + B1 * fj + D1 * fk;
        const float pz0 = C2 + A2 * fi + B2 * fj + D2 * fk;
        const float px1 = px0 + D0;          // voxel k+1, incremental
        const float py1 = py0 + D1;
        const float pz1 = pz0 + D2;

        const f32x4 ra = sample(lds4, px0, py0, pz0);
        const f32x4 rb = sample(lds4, px1, py1, pz1);

        const f32x2 w0 = { ra.x, rb.x };
        const f32x2 w1 = { ra.y, rb.y };
        const f32x2 w2 = { ra.z, rb.z };
        const f32x2 w3 = { ra.w, rb.w };
        *reinterpret_cast<f32x2*>(o0 + n) = w0;
        *reinterpret_cast<f32x2*>(o1 + n) = w1;
        *reinterpret_cast<f32x2*>(o2 + n) = w2;
        *reinterpret_cast<f32x2*>(o3 + n) = w3;

        // advance by 2*THREADS = 1024 = 21*48 + 16 in (i,j,k)
        n += 2 * THREADS;
        k += 16;
        if (k >= NVOX) { k -= NVOX; j += 22; } else { j += 21; }
        if (j >= NVOX) { j -= NVOX; i += 1; }
    }
}

extern "C" void kernel_launch(void* const* d_in, const int* in_sizes, int n_in,
                              void* d_out, int out_size, void* d_ws, size_t ws_size,
                              hipStream_t stream) {
    const float* feats = (const float*)d_in[0];
    const float* Kcam  = (const float*)d_in[1];
    const float* vmax  = (const float*)d_in[2];
    const float* vmin  = (const float*)d_in[3];
    // d_in[4] = nvox (48), baked in as NVOX
    float* out = (float*)d_out;

    dim3 grid(FDIM / 4, QUARTERS, NR);   // 16 x 4 x 8 = 512 blocks
    dim3 block(THREADS);
    proj_splat_kernel<<<grid, block, 0, stream>>>(feats, Kcam, vmax, vmin, out);
}